// Round 3
// baseline (372.343 us; speedup 1.0000x reference)
//
#include <hip/hip_runtime.h>
#include <math.h>

#define B_ 4
#define T_ 128
#define V_ 50257
#define D_ 512
#define NROWS 512           // B*T
#define GAMMA2_ 0.1f

// ---------------- old fused path (fallback) ----------------
#define BK 32
#define KC 1600             // k per split (multiple of BK)
#define SPLITK 32           // 32*1600 = 51200 >= 50257
#define NIT (KC / BK)
#define LDA 40
#define LDB 40
#define SLICE (NROWS * D_)  // floats per slice
#define WS_PART_OFF 1024

// ---------------- new bf16 path ----------------
#define SPLITK2 48
#define KC2 1056            // 48*1056 = 50688 >= 50257
#define KP 50688            // padded K
#define KU 3168             // 16-elem units per row (KP/16)
#define NPB_X 1024          // X-prep blocks (row = bid>>1, half = bid&1)
#define NPB_W 1024          // W-prep blocks (grid-stride cells)
#define WCELLS (D_ * KU)    // 512*3168 = 1622016
#define ACC_BYTES 4096
#define XB_BYTES ((size_t)NROWS * KP * 2)
#define WT_BYTES ((size_t)D_ * KP * 2)
#define PART2_BYTES ((size_t)SPLITK2 * SLICE * 4)
#define NEED_NEW (ACC_BYTES + XB_BYTES + WT_BYTES + PART2_BYTES)

typedef __attribute__((ext_vector_type(8))) short s8v;     // 8 bf16 (4 VGPRs)
typedef __attribute__((ext_vector_type(4))) float f4v;     // MFMA C/D

__device__ inline unsigned int pack2bf(float f0, float f1) {
    unsigned int u0 = __float_as_uint(f0);
    unsigned int u1 = __float_as_uint(f1);
    u0 += 0x7fffu + ((u0 >> 16) & 1u);
    u1 += 0x7fffu + ((u1 >> 16) & 1u);
    return (u0 >> 16) | (u1 & 0xffff0000u);
}

// LDS-only barrier (old path): waits lgkmcnt(0), leaves vmcnt in flight.
__device__ inline void sync_lds() {
    __builtin_amdgcn_s_waitcnt(0xC07F);
    __builtin_amdgcn_s_barrier();
}

__device__ inline float wave_reduce(float v) {
    #pragma unroll
    for (int o = 32; o > 0; o >>= 1) v += __shfl_down(v, o, 64);
    return v;
}

// async global->LDS, 16B per lane; lds dest = wave-uniform base + lane*16
__device__ __forceinline__ void gload16(const unsigned short* g, unsigned short* l) {
    __builtin_amdgcn_global_load_lds(
        (const __attribute__((address_space(1))) unsigned int*)g,
        (__attribute__((address_space(3))) unsigned int*)l, 16, 0, 0);
}

// ---------------- misc body: nll, coverage, dec_len sums ----------------
__device__ void misc_body(int bid,
                          const float* __restrict__ output_mle,
                          const float* __restrict__ attn,
                          const float* __restrict__ cover,
                          const int* __restrict__ trg,
                          const int* __restrict__ dec_mask,
                          const int* __restrict__ dec_len,
                          float* __restrict__ acc) {
    if (bid < 64) {
        float s = 0.f;
        const float4* a4 = (const float4*)attn;
        const float4* c4 = (const float4*)cover;
        for (int i4 = bid * 256 + threadIdx.x; i4 < 65536; i4 += 64 * 256) {
            float4 a = a4[i4];
            float4 c = c4[i4];
            int b = i4 >> 14;
            int t = (i4 << 2) & (T_ - 1);
            int4 m = *(const int4*)&dec_mask[(b << 7) + t];
            s += m.x ? 0.f : fminf(a.x, c.x);
            s += m.y ? 0.f : fminf(a.y, c.y);
            s += m.z ? 0.f : fminf(a.z, c.z);
            s += m.w ? 0.f : fminf(a.w, c.w);
        }
        s = wave_reduce(s);
        if ((threadIdx.x & 63) == 0) atomicAdd(&acc[2], s);
    } else {
        float lp = 0.f, cnt = 0.f;
        for (int i = threadIdx.x; i < NROWS; i += 256) {
            int tg = trg[i];
            if (tg != 0) {
                lp += __logf(output_mle[(size_t)i * V_ + tg]);
                cnt += 1.f;
            }
        }
        lp = wave_reduce(lp); cnt = wave_reduce(cnt);
        if ((threadIdx.x & 63) == 0) { atomicAdd(&acc[0], lp); atomicAdd(&acc[1], cnt); }
        if (threadIdx.x < B_) atomicAdd(&acc[3], (float)dec_len[threadIdx.x]);
    }
}

__global__ void misc_kernel(const float* __restrict__ output_mle,
                            const float* __restrict__ attn,
                            const float* __restrict__ cover,
                            const int* __restrict__ trg,
                            const int* __restrict__ dec_mask,
                            const int* __restrict__ dec_len,
                            float* __restrict__ acc) {
    misc_body(blockIdx.x, output_mle, attn, cover, trg, dec_mask, dec_len, acc);
}

// ---------------- prep: Xb = bf16(exp(X)); Wt = bf16(W^T); + misc. NO LDS. ----
__launch_bounds__(256)
__global__ void prep_kernel(const float* __restrict__ X,
                            const float* __restrict__ W,
                            const float* __restrict__ attn,
                            const float* __restrict__ cover,
                            const int* __restrict__ trg,
                            const int* __restrict__ dec_mask,
                            const int* __restrict__ dec_len,
                            float* __restrict__ acc,
                            unsigned short* __restrict__ Xb,
                            unsigned short* __restrict__ Wt) {
    const int bid = blockIdx.x;
    const int tid = threadIdx.x;
    if (bid < NPB_X) {
        // X: exp + bf16, zero-pad [V_, KP). block = (row, half); 16 elems/unit.
        const int row  = bid >> 1;
        const int base = (bid & 1) * (KU / 2);     // 1584 units per half
        const float* src = X + (size_t)row * V_;
        unsigned short* dst = Xb + (size_t)row * KP;
        #pragma unroll 4
        for (int i = tid; i < KU / 2; i += 256) {
            int k16 = (base + i) << 4;
            unsigned int pk[8];
            if (k16 + 16 <= V_) {
                float4 v0 = *(const float4*)(src + k16);
                float4 v1 = *(const float4*)(src + k16 + 4);
                float4 v2 = *(const float4*)(src + k16 + 8);
                float4 v3 = *(const float4*)(src + k16 + 12);
                pk[0] = pack2bf(__expf(v0.x), __expf(v0.y));
                pk[1] = pack2bf(__expf(v0.z), __expf(v0.w));
                pk[2] = pack2bf(__expf(v1.x), __expf(v1.y));
                pk[3] = pack2bf(__expf(v1.z), __expf(v1.w));
                pk[4] = pack2bf(__expf(v2.x), __expf(v2.y));
                pk[5] = pack2bf(__expf(v2.z), __expf(v2.w));
                pk[6] = pack2bf(__expf(v3.x), __expf(v3.y));
                pk[7] = pack2bf(__expf(v3.z), __expf(v3.w));
            } else {
                #pragma unroll
                for (int p = 0; p < 8; p++) {
                    float e0 = (k16 + 2 * p     < V_) ? __expf(src[k16 + 2 * p])     : 0.f;
                    float e1 = (k16 + 2 * p + 1 < V_) ? __expf(src[k16 + 2 * p + 1]) : 0.f;
                    pk[p] = pack2bf(e0, e1);
                }
            }
            *(uint4*)&dst[k16]     = *(uint4*)&pk[0];
            *(uint4*)&dst[k16 + 8] = *(uint4*)&pk[4];
        }
    } else if (bid < NPB_X + NPB_W) {
        // W^T without LDS: cell = (d, k16). Wave lanes = consecutive d ->
        // each of the 16 loads is a coalesced 256B row segment; writes are
        // 32B k-contiguous per thread. 16 independent loads/thread in flight.
        const int c0 = (bid - NPB_X) * 256 + tid;
        #pragma unroll 2
        for (int c = c0; c < WCELLS; c += NPB_W * 256) {
            int d   = c & (D_ - 1);
            int k16 = (c >> 9) << 4;
            const float* src = W + d;
            float v[16];
            if (k16 + 16 <= V_) {
                #pragma unroll
                for (int j = 0; j < 16; j++) v[j] = src[(size_t)(k16 + j) * D_];
            } else {
                #pragma unroll
                for (int j = 0; j < 16; j++)
                    v[j] = (k16 + j < V_) ? src[(size_t)(k16 + j) * D_] : 0.f;
            }
            unsigned int pk[8];
            #pragma unroll
            for (int p = 0; p < 8; p++) pk[p] = pack2bf(v[2 * p], v[2 * p + 1]);
            unsigned short* dst = Wt + (size_t)d * KP + k16;
            *(uint4*)&dst[0] = *(uint4*)&pk[0];
            *(uint4*)&dst[8] = *(uint4*)&pk[4];
        }
    } else {
        misc_body(bid - (NPB_X + NPB_W), X, attn, cover, trg, dec_mask, dec_len, acc);
    }
}

// ---------------- gemm2: bf16, global_load_lds, dbuf, XCD-clustered splits ----
__launch_bounds__(256)
__global__ void gemm2_kernel(const unsigned short* __restrict__ Xb,
                             const unsigned short* __restrict__ Wt,
                             float* __restrict__ part) {
    __shared__ __align__(16) unsigned short As[2][128 * 32];  // 2 x 8KB
    __shared__ __align__(16) unsigned short Bs[2][128 * 32];  // 2 x 8KB

    // XCD-cluster swizzle: all 16 tiles of split s land on XCD s%8, so the
    // shared A/B K-window stays in that XCD's L2 (tiles run in lockstep).
    const int bx   = blockIdx.x;
    const int xcd  = bx & 7;
    const int j    = bx >> 3;            // 0..95
    const int s    = xcd + 8 * (j >> 4); // 0..47
    const int tile = j & 15;
    const int i0   = (tile & 3) * 128;
    const int d0   = (tile >> 2) * 128;
    const size_t ks = (size_t)s * KC2;

    const int tid  = threadIdx.x;
    const int lane = tid & 63;
    const int wave = tid >> 6;
    const int wm   = (wave & 1) * 64;
    const int wn   = (wave >> 1) * 64;
    const int l15  = lane & 15;
    const int l4   = lane >> 4;

    // gload mapping: lane -> (row = wave*16 + lane/4, kchunk = (lane&3)*8)
    const int grow = wave * 16 + (lane >> 2);
    const int gk8  = (lane & 3) * 8;
    const unsigned short* gA0 = Xb + (size_t)(i0 + grow) * KP + ks + gk8;
    const unsigned short* gA1 = gA0 + (size_t)64 * KP;
    const unsigned short* gB0 = Wt + (size_t)(d0 + grow) * KP + ks + gk8;
    const unsigned short* gB1 = gB0 + (size_t)64 * KP;

    f4v acc[4][4];
    #pragma unroll
    for (int a = 0; a < 4; a++)
        #pragma unroll
        for (int b = 0; b < 4; b++) acc[a][b] = (f4v)0.f;

    auto stage = [&](unsigned short* Ab, unsigned short* Bb, int off) {
        gload16(gA0 + off, Ab + wave * 512);
        gload16(gA1 + off, Ab + wave * 512 + 2048);
        gload16(gB0 + off, Bb + wave * 512);
        gload16(gB1 + off, Bb + wave * 512 + 2048);
    };
    auto compute = [&](const unsigned short* Ab, const unsigned short* Bb) {
        s8v af[4], bfr[4];
        #pragma unroll
        for (int mi = 0; mi < 4; mi++)
            af[mi] = *(const s8v*)&Ab[(wm + mi * 16 + l15) * 32 + l4 * 8];
        #pragma unroll
        for (int ni = 0; ni < 4; ni++)
            bfr[ni] = *(const s8v*)&Bb[(wn + ni * 16 + l15) * 32 + l4 * 8];
        #pragma unroll
        for (int mi = 0; mi < 4; mi++)
            #pragma unroll
            for (int ni = 0; ni < 4; ni++)
                acc[mi][ni] = __builtin_amdgcn_mfma_f32_16x16x32_bf16(
                    af[mi], bfr[ni], acc[mi][ni], 0, 0, 0);
    };

    // 33 K-tiles of 32: prologue + 16 dbuf pairs + epilogue (tile 32 in buf0)
    stage(As[0], Bs[0], 0);
    __syncthreads();                      // drain: buf0 ready
    #pragma unroll 1
    for (int it = 0; it + 2 < KC2 / 32; it += 2) {
        stage(As[1], Bs[1], (it + 1) * 32);   // issue next BEFORE compute
        compute(As[0], Bs[0]);
        __syncthreads();                      // vmcnt(0)+barrier: buf1 ready
        stage(As[0], Bs[0], (it + 2) * 32);
        compute(As[1], Bs[1]);
        __syncthreads();
    }
    compute(As[0], Bs[0]);

    float* dst = part + (size_t)s * SLICE;
    #pragma unroll
    for (int mi = 0; mi < 4; mi++) {
        #pragma unroll
        for (int ni = 0; ni < 4; ni++) {
            int col = d0 + wn + ni * 16 + l15;
            #pragma unroll
            for (int r = 0; r < 4; r++) {
                int row = i0 + wm + mi * 16 + l4 * 4 + r;
                dst[row * D_ + col] = acc[mi][ni][r];
            }
        }
    }
}

// ---------------- old fused gemm (fallback) ----------------
__launch_bounds__(256)
__global__ void gemm_kernel(const float* __restrict__ X,
                            const float* __restrict__ W,
                            float* __restrict__ part,
                            int use_atomic) {
    __shared__ __align__(16) short As[128 * LDA];
    __shared__ __align__(16) short Bs[128 * LDB];

    const int bx   = blockIdx.x;
    const int tile = bx & 15;
    const int s    = bx >> 4;
    const int i0   = (tile & 3) * 128;
    const int d0   = (tile >> 2) * 128;
    const int ks   = s * KC;
    const int ke   = min(ks + KC, V_);

    const int tid  = threadIdx.x;
    const int lane = tid & 63;
    const int wave = tid >> 6;
    const int wm   = (wave & 1) * 64;
    const int wn   = (wave >> 1) * 64;
    const int l15  = lane & 15;
    const int l4   = lane >> 4;

    const int ar   = tid >> 1;
    const int akh  = (tid & 1) * 16;
    const int bn2  = (tid & 63) * 2;
    const int bkq  = (tid >> 6) * 8;

    f4v acc[4][4];
    #pragma unroll
    for (int a = 0; a < 4; a++)
        #pragma unroll
        for (int b = 0; b < 4; b++) acc[a][b] = (f4v)0.f;

    auto stageA = [&](const float4 (&ab)[4]) {
        const float* f = (const float*)&ab[0];
        unsigned int au[8];
        #pragma unroll
        for (int p = 0; p < 8; p++)
            au[p] = pack2bf(__expf(f[2 * p]), __expf(f[2 * p + 1]));
        *(uint4*)&As[ar * LDA + akh]     = *(const uint4*)&au[0];
        *(uint4*)&As[ar * LDA + akh + 8] = *(const uint4*)&au[4];
    };
    auto stageB = [&](const float2 (&bb)[8]) {
        unsigned int r0[4], r1[4];
        #pragma unroll
        for (int p = 0; p < 4; p++) {
            r0[p] = pack2bf(bb[2 * p].x, bb[2 * p + 1].x);
            r1[p] = pack2bf(bb[2 * p].y, bb[2 * p + 1].y);
        }
        *(uint4*)&Bs[bn2 * LDB + bkq]       = *(const uint4*)&r0[0];
        *(uint4*)&Bs[(bn2 + 1) * LDB + bkq] = *(const uint4*)&r1[0];
    };
    auto domfma = [&]() {
        s8v af[4], bfr[4];
        #pragma unroll
        for (int mi = 0; mi < 4; mi++)
            af[mi] = *(const s8v*)&As[(wm + mi * 16 + l15) * LDA + l4 * 8];
        #pragma unroll
        for (int ni = 0; ni < 4; ni++)
            bfr[ni] = *(const s8v*)&Bs[(wn + ni * 16 + l15) * LDB + l4 * 8];
        #pragma unroll
        for (int mi = 0; mi < 4; mi++)
            #pragma unroll
            for (int ni = 0; ni < 4; ni++)
                acc[mi][ni] = __builtin_amdgcn_mfma_f32_16x16x32_bf16(
                    af[mi], bfr[ni], acc[mi][ni], 0, 0, 0);
    };
    auto issue = [&](float4 (&ab)[4], float2 (&bb)[8], const float* ap, const float* bp) {
        #pragma unroll
        for (int q = 0; q < 4; q++) ab[q] = *(const float4*)(ap + q * 4);
        #pragma unroll
        for (int j = 0; j < 8; j++) bb[j] = *(const float2*)(bp + (size_t)j * D_);
    };

    if (ks + KC <= V_) {
        const float* ap = X + (size_t)(i0 + ar) * V_ + ks + akh;
        const float* bp = W + d0 + bn2 + (size_t)(ks + bkq) * D_;
        float4 a0[4], a1[4];
        float2 b0[8], b1[8];
        issue(a0, b0, ap, bp);
        #pragma unroll 1
        for (int it = 0; it < NIT; it += 2) {
            ap += BK; bp += (size_t)BK * D_;
            if (it + 1 < NIT) issue(a1, b1, ap, bp);
            sync_lds();
            stageA(a0); stageB(b0);
            sync_lds();
            domfma();

            ap += BK; bp += (size_t)BK * D_;
            if (it + 2 < NIT) issue(a0, b0, ap, bp);
            sync_lds();
            stageA(a1); stageB(b1);
            sync_lds();
            domfma();
        }
    } else {
        const float* Abase = X + (size_t)(i0 + ar) * V_;
        const float* Bbase = W + d0 + bn2;
        for (int k0 = ks; k0 < ke; k0 += BK) {
            float4 ab[4];
            float2 bb[8];
            #pragma unroll
            for (int q = 0; q < 4; q++) {
                int gk = min(k0 + akh + q * 4, V_ - 4);
                ab[q] = *(const float4*)(Abase + gk);
            }
            #pragma unroll
            for (int j = 0; j < 8; j++) {
                int gk = min(k0 + bkq + j, V_ - 1);
                bb[j] = *(const float2*)(Bbase + (size_t)gk * D_);
            }
            sync_lds();
            {
                unsigned int au[8];
                const float* f = (const float*)&ab[0];
                #pragma unroll
                for (int p = 0; p < 8; p++) {
                    int g0 = k0 + akh + 2 * p;
                    float e0 = (g0     < ke) ? __expf(f[2 * p])     : 0.f;
                    float e1 = (g0 + 1 < ke) ? __expf(f[2 * p + 1]) : 0.f;
                    au[p] = pack2bf(e0, e1);
                }
                *(uint4*)&As[ar * LDA + akh]     = *(const uint4*)&au[0];
                *(uint4*)&As[ar * LDA + akh + 8] = *(const uint4*)&au[4];
            }
            {
                unsigned int r0[4], r1[4];
                #pragma unroll
                for (int p = 0; p < 4; p++) {
                    int g0 = k0 + bkq + 2 * p;
                    float x0 = (g0     < ke) ? bb[2 * p].x     : 0.f;
                    float x1 = (g0 + 1 < ke) ? bb[2 * p + 1].x : 0.f;
                    float y0 = (g0     < ke) ? bb[2 * p].y     : 0.f;
                    float y1 = (g0 + 1 < ke) ? bb[2 * p + 1].y : 0.f;
                    r0[p] = pack2bf(x0, x1);
                    r1[p] = pack2bf(y0, y1);
                }
                *(uint4*)&Bs[bn2 * LDB + bkq]       = *(const uint4*)&r0[0];
                *(uint4*)&Bs[(bn2 + 1) * LDB + bkq] = *(const uint4*)&r1[0];
            }
            sync_lds();
            domfma();
        }
    }

    float* dst = part + (use_atomic ? 0 : (size_t)s * SLICE);
    #pragma unroll
    for (int mi = 0; mi < 4; mi++) {
        #pragma unroll
        for (int ni = 0; ni < 4; ni++) {
            int col = d0 + wn + ni * 16 + l15;
            #pragma unroll
            for (int r = 0; r < 4; r++) {
                int row = i0 + wm + mi * 16 + l4 * 4 + r;
                if (use_atomic) atomicAdd(&dst[row * D_ + col], acc[mi][ni][r]);
                else            dst[row * D_ + col] = acc[mi][ni][r];
            }
        }
    }
}

// ---------------- ot: reduce slices + mean_i cos(pred_i, W[trg_i]) ----------------
// one row per block; 4 waves split slices, LDS-combine, wave0 finishes.
__global__ void ot_kernel(const float* __restrict__ part,
                          const float* __restrict__ W,
                          const int* __restrict__ trg,
                          float* __restrict__ acc,
                          int nsl) {
    __shared__ float Ps[4][D_];
    int wave = threadIdx.x >> 6, lane = threadIdx.x & 63;
    int row  = blockIdx.x;
    const size_t off = (size_t)row * D_ + lane * 8;

    float4 p0 = {0, 0, 0, 0}, p1 = {0, 0, 0, 0};
    for (int s = wave; s < nsl; s += 4) {
        const float4* ps = (const float4*)(part + (size_t)s * SLICE + off);
        float4 q0 = ps[0], q1 = ps[1];
        p0.x += q0.x; p0.y += q0.y; p0.z += q0.z; p0.w += q0.w;
        p1.x += q1.x; p1.y += q1.y; p1.z += q1.z; p1.w += q1.w;
    }
    *(float4*)&Ps[wave][lane * 8]     = p0;
    *(float4*)&Ps[wave][lane * 8 + 4] = p1;
    __syncthreads();
    if (wave == 0) {
        float4 s0 = {0, 0, 0, 0}, s1 = {0, 0, 0, 0};
        #pragma unroll
        for (int w = 0; w < 4; w++) {
            float4 q0 = *(const float4*)&Ps[w][lane * 8];
            float4 q1 = *(const float4*)&Ps[w][lane * 8 + 4];
            s0.x += q0.x; s0.y += q0.y; s0.z += q0.z; s0.w += q0.w;
            s1.x += q1.x; s1.y += q1.y; s1.z += q1.z; s1.w += q1.w;
        }
        const float4* t4 = (const float4*)(W + (size_t)trg[row] * D_ + lane * 8);
        float4 t0 = t4[0], t1 = t4[1];

        float dot = s0.x * t0.x + s0.y * t0.y + s0.z * t0.z + s0.w * t0.w
                  + s1.x * t1.x + s1.y * t1.y + s1.z * t1.z + s1.w * t1.w;
        float nn  = s0.x * s0.x + s0.y * s0.y + s0.z * s0.z + s0.w * s0.w
                  + s1.x * s1.x + s1.y * s1.y + s1.z * s1.z + s1.w * s1.w;
        float tt  = t0.x * t0.x + t0.y * t0.y + t0.z * t0.z + t0.w * t0.w
                  + t1.x * t1.x + t1.y * t1.y + t1.z * t1.z + t1.w * t1.w;

        dot = wave_reduce(dot); nn = wave_reduce(nn); tt = wave_reduce(tt);
        if (lane == 0)
            atomicAdd(&acc[4], (dot / sqrtf(nn * tt)) * (1.0f / (float)NROWS));
    }
}

// ---------------- finalize ----------------
__global__ void finalize_kernel(const float* __restrict__ acc, float* __restrict__ out) {
    if (threadIdx.x == 0)
        out[0] = -acc[0] / acc[1] + acc[2] / acc[3] + GAMMA2_ + acc[4];
}

extern "C" void kernel_launch(void* const* d_in, const int* in_sizes, int n_in,
                              void* d_out, int out_size, void* d_ws, size_t ws_size,
                              hipStream_t stream) {
    const float* output_mle = (const float*)d_in[0];
    const float* attn       = (const float*)d_in[1];
    const float* cover      = (const float*)d_in[2];
    const int*   trg        = (const int*)d_in[3];
    const int*   dec_mask   = (const int*)d_in[4];
    const int*   dec_len    = (const int*)d_in[5];
    const float* W          = (const float*)d_in[6];
    float* out  = (float*)d_out;
    float* acc  = (float*)d_ws;

    const bool newpath = (ws_size >= NEED_NEW);   // constant across calls: graph-safe

    if (newpath) {
        unsigned short* Xb = (unsigned short*)((char*)d_ws + ACC_BYTES);
        unsigned short* Wt = (unsigned short*)((char*)d_ws + ACC_BYTES + XB_BYTES);
        float* part2 = (float*)((char*)d_ws + ACC_BYTES + XB_BYTES + WT_BYTES);
        hipMemsetAsync(d_ws, 0, ACC_BYTES, stream);
        prep_kernel<<<NPB_X + NPB_W + 65, 256, 0, stream>>>(
            output_mle, W, attn, cover, trg, dec_mask, dec_len, acc, Xb, Wt);
        gemm2_kernel<<<16 * SPLITK2, 256, 0, stream>>>(Xb, Wt, part2);
        ot_kernel<<<NROWS, 256, 0, stream>>>(part2, W, trg, acc, SPLITK2);
        finalize_kernel<<<1, 64, 0, stream>>>(acc, out);
    } else {
        float* part = acc + WS_PART_OFF;
        const size_t need = (size_t)WS_PART_OFF * 4 + (size_t)SPLITK * SLICE * 4;
        const bool partial = (ws_size >= need);
        if (partial) {
            hipMemsetAsync(d_ws, 0, WS_PART_OFF * sizeof(float), stream);
        } else {
            hipMemsetAsync(d_ws, 0, (WS_PART_OFF + SLICE) * sizeof(float), stream);
        }
        misc_kernel<<<65, 256, 0, stream>>>(output_mle, attn, cover, trg, dec_mask, dec_len, acc);
        gemm_kernel<<<16 * SPLITK, 256, 0, stream>>>(output_mle, W, part, partial ? 0 : 1);
        ot_kernel<<<NROWS, 256, 0, stream>>>(part, W, trg, acc, partial ? SPLITK : 1);
        finalize_kernel<<<1, 64, 0, stream>>>(acc, out);
    }
}

// Round 4
// 315.540 us; speedup vs baseline: 1.1800x; 1.1800x over previous
//
#include <hip/hip_runtime.h>
#include <math.h>

#define B_ 4
#define T_ 128
#define V_ 50257
#define D_ 512
#define NROWS 512           // B*T
#define GAMMA2_ 0.1f

#define BK 32
#define KC 1600             // k per split (multiple of BK)
#define SPLITK 32           // 32*1600 = 51200 >= 50257
#define NIT (KC / BK)       // 50 iters in full splits
#define LDA 40              // As row stride in shorts (32 + 8 pad)
#define LDB 40              // Bs row stride in shorts

#define SLICE (NROWS * D_)  // 262144 floats = 1 MB per split slice

typedef __attribute__((ext_vector_type(8))) short s8v;     // 8 bf16 (4 VGPRs)
typedef __attribute__((ext_vector_type(4))) float f4v;     // MFMA C/D

// ws layout (floats): [0..4]=acc sums, [1024..] partial slices (or pred in fallback)
#define WS_PART_OFF 1024

__device__ inline unsigned int pack2bf(float f0, float f1) {
    unsigned int u0 = __float_as_uint(f0);
    unsigned int u1 = __float_as_uint(f1);
    u0 += 0x7fffu + ((u0 >> 16) & 1u);
    u1 += 0x7fffu + ((u1 >> 16) & 1u);
    return (u0 >> 16) | (u1 & 0xffff0000u);
}

// LDS-only barrier: waits lgkmcnt(0), leaves vmcnt (global prefetch) in flight.
__device__ inline void sync_lds() {
    __builtin_amdgcn_s_waitcnt(0xC07F);
    __builtin_amdgcn_s_barrier();
}

__device__ inline float wave_reduce(float v) {
    #pragma unroll
    for (int o = 32; o > 0; o >>= 1) v += __shfl_down(v, o, 64);
    return v;
}

// ---------------- misc: nll, coverage, dec_len sums ----------------
__global__ void misc_kernel(const float* __restrict__ output_mle,
                            const float* __restrict__ attn,
                            const float* __restrict__ cover,
                            const int* __restrict__ trg,
                            const int* __restrict__ dec_mask,
                            const int* __restrict__ dec_len,
                            float* __restrict__ acc) {
    int bid = blockIdx.x;
    if (bid < 64) {
        float s = 0.f;
        const float4* a4 = (const float4*)attn;
        const float4* c4 = (const float4*)cover;
        for (int i4 = bid * 256 + threadIdx.x; i4 < 65536; i4 += 64 * 256) {
            float4 a = a4[i4];
            float4 c = c4[i4];
            int b = i4 >> 14;
            int t = (i4 << 2) & (T_ - 1);
            int4 m = *(const int4*)&dec_mask[(b << 7) + t];
            s += m.x ? 0.f : fminf(a.x, c.x);
            s += m.y ? 0.f : fminf(a.y, c.y);
            s += m.z ? 0.f : fminf(a.z, c.z);
            s += m.w ? 0.f : fminf(a.w, c.w);
        }
        s = wave_reduce(s);
        if ((threadIdx.x & 63) == 0) atomicAdd(&acc[2], s);
    } else {
        float lp = 0.f, cnt = 0.f;
        for (int i = threadIdx.x; i < NROWS; i += 256) {
            int tg = trg[i];
            if (tg != 0) {
                lp += __logf(output_mle[(size_t)i * V_ + tg]);
                cnt += 1.f;
            }
        }
        lp = wave_reduce(lp); cnt = wave_reduce(cnt);
        if ((threadIdx.x & 63) == 0) { atomicAdd(&acc[0], lp); atomicAdd(&acc[1], cnt); }
        if (threadIdx.x < B_) atomicAdd(&acc[3], (float)dec_len[threadIdx.x]);
    }
}

// ---------------- GEMM: part[s] = exp(X)*W over split s (bf16 MFMA) ----------
// XCD-cluster swizzle: all 16 tiles of split s land on XCD s&7 (dispatch is
// round-robin by blockIdx % 8), so the split's streaming X/W K-panels
// (~3.2 MB window) are served from that XCD's L2 instead of re-fetched.
__launch_bounds__(256)
__global__ void gemm_kernel(const float* __restrict__ X,
                            const float* __restrict__ W,
                            float* __restrict__ part,
                            int use_atomic) {
    __shared__ __align__(16) short As[128 * LDA];
    __shared__ __align__(16) short Bs[128 * LDB];

    const int bx   = blockIdx.x;
    const int xcd  = bx & 7;
    const int j    = bx >> 3;            // 0..63
    const int s    = xcd + 8 * (j >> 4); // 0..31 (bijective with tile)
    const int tile = j & 15;
    const int i0   = (tile & 3) * 128;
    const int d0   = (tile >> 2) * 128;
    const int ks   = s * KC;
    const int ke   = min(ks + KC, V_);

    const int tid  = threadIdx.x;
    const int lane = tid & 63;
    const int wave = tid >> 6;
    const int wm   = (wave & 1) * 64;
    const int wn   = (wave >> 1) * 64;
    const int l15  = lane & 15;
    const int l4   = lane >> 4;

    const int ar   = tid >> 1;            // A row 0..127
    const int akh  = (tid & 1) * 16;      // A k-half
    const int bn2  = (tid & 63) * 2;      // B col pair
    const int bkq  = (tid >> 6) * 8;      // B k-octet

    f4v acc[4][4];
    #pragma unroll
    for (int a = 0; a < 4; a++)
        #pragma unroll
        for (int b = 0; b < 4; b++) acc[a][b] = (f4v)0.f;

    auto stageA = [&](const float4 (&ab)[4]) {
        const float* f = (const float*)&ab[0];
        unsigned int au[8];
        #pragma unroll
        for (int p = 0; p < 8; p++)
            au[p] = pack2bf(__expf(f[2 * p]), __expf(f[2 * p + 1]));
        *(uint4*)&As[ar * LDA + akh]     = *(const uint4*)&au[0];
        *(uint4*)&As[ar * LDA + akh + 8] = *(const uint4*)&au[4];
    };
    auto stageB = [&](const float2 (&bb)[8]) {
        unsigned int r0[4], r1[4];
        #pragma unroll
        for (int p = 0; p < 4; p++) {
            r0[p] = pack2bf(bb[2 * p].x, bb[2 * p + 1].x);
            r1[p] = pack2bf(bb[2 * p].y, bb[2 * p + 1].y);
        }
        *(uint4*)&Bs[bn2 * LDB + bkq]       = *(const uint4*)&r0[0];
        *(uint4*)&Bs[(bn2 + 1) * LDB + bkq] = *(const uint4*)&r1[0];
    };
    auto domfma = [&]() {
        s8v af[4], bfr[4];
        #pragma unroll
        for (int mi = 0; mi < 4; mi++)
            af[mi] = *(const s8v*)&As[(wm + mi * 16 + l15) * LDA + l4 * 8];
        #pragma unroll
        for (int ni = 0; ni < 4; ni++)
            bfr[ni] = *(const s8v*)&Bs[(wn + ni * 16 + l15) * LDB + l4 * 8];
        #pragma unroll
        for (int mi = 0; mi < 4; mi++)
            #pragma unroll
            for (int ni = 0; ni < 4; ni++)
                acc[mi][ni] = __builtin_amdgcn_mfma_f32_16x16x32_bf16(
                    af[mi], bfr[ni], acc[mi][ni], 0, 0, 0);
    };
    auto issue = [&](float4 (&ab)[4], float2 (&bb)[8], const float* ap, const float* bp) {
        #pragma unroll
        for (int q = 0; q < 4; q++) ab[q] = *(const float4*)(ap + q * 4);
        #pragma unroll
        for (int j2 = 0; j2 < 8; j2++) bb[j2] = *(const float2*)(bp + (size_t)j2 * D_);
    };

    if (ks + KC <= V_) {
        // full split: clamp-free pipelined loop; barriers never drain vmcnt
        const float* ap = X + (size_t)(i0 + ar) * V_ + ks + akh;
        const float* bp = W + d0 + bn2 + (size_t)(ks + bkq) * D_;
        float4 a0[4], a1[4];
        float2 b0[8], b1[8];
        issue(a0, b0, ap, bp);
        #pragma unroll 1
        for (int it = 0; it < NIT; it += 2) {
            ap += BK; bp += (size_t)BK * D_;
            if (it + 1 < NIT) issue(a1, b1, ap, bp);
            sync_lds();
            stageA(a0); stageB(b0);
            sync_lds();
            domfma();

            ap += BK; bp += (size_t)BK * D_;
            if (it + 2 < NIT) issue(a0, b0, ap, bp);
            sync_lds();
            stageA(a1); stageB(b1);
            sync_lds();
            domfma();
        }
    } else {
        // last split: masked single-buffered loop
        const float* Abase = X + (size_t)(i0 + ar) * V_;
        const float* Bbase = W + d0 + bn2;
        for (int k0 = ks; k0 < ke; k0 += BK) {
            float4 ab[4];
            float2 bb[8];
            #pragma unroll
            for (int q = 0; q < 4; q++) {
                int gk = min(k0 + akh + q * 4, V_ - 4);
                ab[q] = *(const float4*)(Abase + gk);
            }
            #pragma unroll
            for (int j2 = 0; j2 < 8; j2++) {
                int gk = min(k0 + bkq + j2, V_ - 1);
                bb[j2] = *(const float2*)(Bbase + (size_t)gk * D_);
            }
            sync_lds();
            {
                unsigned int au[8];
                const float* f = (const float*)&ab[0];
                #pragma unroll
                for (int p = 0; p < 8; p++) {
                    int g0 = k0 + akh + 2 * p;
                    float e0 = (g0     < ke) ? __expf(f[2 * p])     : 0.f;
                    float e1 = (g0 + 1 < ke) ? __expf(f[2 * p + 1]) : 0.f;
                    au[p] = pack2bf(e0, e1);
                }
                *(uint4*)&As[ar * LDA + akh]     = *(const uint4*)&au[0];
                *(uint4*)&As[ar * LDA + akh + 8] = *(const uint4*)&au[4];
            }
            {
                unsigned int r0[4], r1[4];
                #pragma unroll
                for (int p = 0; p < 4; p++) {
                    int g0 = k0 + bkq + 2 * p;
                    float x0 = (g0     < ke) ? bb[2 * p].x     : 0.f;
                    float x1 = (g0 + 1 < ke) ? bb[2 * p + 1].x : 0.f;
                    float y0 = (g0     < ke) ? bb[2 * p].y     : 0.f;
                    float y1 = (g0 + 1 < ke) ? bb[2 * p + 1].y : 0.f;
                    r0[p] = pack2bf(x0, x1);
                    r1[p] = pack2bf(y0, y1);
                }
                *(uint4*)&Bs[bn2 * LDB + bkq]       = *(const uint4*)&r0[0];
                *(uint4*)&Bs[(bn2 + 1) * LDB + bkq] = *(const uint4*)&r1[0];
            }
            sync_lds();
            domfma();
        }
    }

    // epilogue: C/D layout col=lane&15, row=(lane>>4)*4+r
    float* dst = part + (use_atomic ? 0 : (size_t)s * SLICE);
    #pragma unroll
    for (int mi = 0; mi < 4; mi++) {
        #pragma unroll
        for (int ni = 0; ni < 4; ni++) {
            int col = d0 + wn + ni * 16 + l15;
            #pragma unroll
            for (int r = 0; r < 4; r++) {
                int row = i0 + wm + mi * 16 + l4 * 4 + r;
                if (use_atomic) atomicAdd(&dst[row * D_ + col], acc[mi][ni][r]);
                else            dst[row * D_ + col] = acc[mi][ni][r];
            }
        }
    }
}

// ---------------- ot: reduce slices + mean_i cos(pred_i, W[trg_i]) ----------------
// one row per block; 4 waves split slices, LDS-combine, wave0 finishes.
__global__ void ot_kernel(const float* __restrict__ part,
                          const float* __restrict__ W,
                          const int* __restrict__ trg,
                          float* __restrict__ acc,
                          int nsl) {
    __shared__ float Ps[4][D_];
    int wave = threadIdx.x >> 6, lane = threadIdx.x & 63;
    int row  = blockIdx.x;
    const size_t off = (size_t)row * D_ + lane * 8;

    float4 p0 = {0, 0, 0, 0}, p1 = {0, 0, 0, 0};
    for (int s = wave; s < nsl; s += 4) {
        const float4* ps = (const float4*)(part + (size_t)s * SLICE + off);
        float4 q0 = ps[0], q1 = ps[1];
        p0.x += q0.x; p0.y += q0.y; p0.z += q0.z; p0.w += q0.w;
        p1.x += q1.x; p1.y += q1.y; p1.z += q1.z; p1.w += q1.w;
    }
    *(float4*)&Ps[wave][lane * 8]     = p0;
    *(float4*)&Ps[wave][lane * 8 + 4] = p1;
    __syncthreads();
    if (wave == 0) {
        float4 s0 = {0, 0, 0, 0}, s1 = {0, 0, 0, 0};
        #pragma unroll
        for (int w = 0; w < 4; w++) {
            float4 q0 = *(const float4*)&Ps[w][lane * 8];
            float4 q1 = *(const float4*)&Ps[w][lane * 8 + 4];
            s0.x += q0.x; s0.y += q0.y; s0.z += q0.z; s0.w += q0.w;
            s1.x += q1.x; s1.y += q1.y; s1.z += q1.z; s1.w += q1.w;
        }
        const float4* t4 = (const float4*)(W + (size_t)trg[row] * D_ + lane * 8);
        float4 t0 = t4[0], t1 = t4[1];

        float dot = s0.x * t0.x + s0.y * t0.y + s0.z * t0.z + s0.w * t0.w
                  + s1.x * t1.x + s1.y * t1.y + s1.z * t1.z + s1.w * t1.w;
        float nn  = s0.x * s0.x + s0.y * s0.y + s0.z * s0.z + s0.w * s0.w
                  + s1.x * s1.x + s1.y * s1.y + s1.z * s1.z + s1.w * s1.w;
        float tt  = t0.x * t0.x + t0.y * t0.y + t0.z * t0.z + t0.w * t0.w
                  + t1.x * t1.x + t1.y * t1.y + t1.z * t1.z + t1.w * t1.w;

        dot = wave_reduce(dot); nn = wave_reduce(nn); tt = wave_reduce(tt);
        if (lane == 0)
            atomicAdd(&acc[4], (dot / sqrtf(nn * tt)) * (1.0f / (float)NROWS));
    }
}

// ---------------- finalize ----------------
__global__ void finalize_kernel(const float* __restrict__ acc, float* __restrict__ out) {
    if (threadIdx.x == 0)
        out[0] = -acc[0] / acc[1] + acc[2] / acc[3] + GAMMA2_ + acc[4];
}

extern "C" void kernel_launch(void* const* d_in, const int* in_sizes, int n_in,
                              void* d_out, int out_size, void* d_ws, size_t ws_size,
                              hipStream_t stream) {
    const float* output_mle = (const float*)d_in[0];
    const float* attn       = (const float*)d_in[1];
    const float* cover      = (const float*)d_in[2];
    const int*   trg        = (const int*)d_in[3];
    const int*   dec_mask   = (const int*)d_in[4];
    const int*   dec_len    = (const int*)d_in[5];
    const float* W          = (const float*)d_in[6];
    float* out  = (float*)d_out;
    float* acc  = (float*)d_ws;
    float* part = acc + WS_PART_OFF;

    const size_t need = (size_t)WS_PART_OFF * 4 + (size_t)SPLITK * SLICE * 4;
    const bool partial = (ws_size >= need);   // constant across calls: graph-safe

    if (partial) {
        hipMemsetAsync(d_ws, 0, WS_PART_OFF * sizeof(float), stream);
    } else {
        hipMemsetAsync(d_ws, 0, (WS_PART_OFF + SLICE) * sizeof(float), stream);
    }
    misc_kernel<<<65, 256, 0, stream>>>(output_mle, attn, cover, trg, dec_mask, dec_len, acc);
    gemm_kernel<<<16 * SPLITK, 256, 0, stream>>>(output_mle, W, part, partial ? 0 : 1);
    ot_kernel<<<NROWS, 256, 0, stream>>>(part, W, trg, acc, partial ? SPLITK : 1);
    finalize_kernel<<<1, 64, 0, stream>>>(acc, out);
}

// Round 5
// 302.143 us; speedup vs baseline: 1.2323x; 1.0443x over previous
//
#include <hip/hip_runtime.h>
#include <math.h>

#define B_ 4
#define T_ 128
#define V_ 50257
#define D_ 512
#define NROWS 512           // B*T
#define GAMMA2_ 0.1f

#define BK 32
#define KC 1600             // k per split (multiple of BK)
#define SPLITK 32           // 32*1600 = 51200 >= 50257
#define NIT (KC / BK)       // 50 iters in full splits (even: dbuf pairs)
#define LDA 40              // As row stride in shorts (32 + 8 pad)
#define LDB 40              // Bs row stride in shorts
#define NMISC 40            // misc blocks fused at grid front (multiple of 8)

#define SLICE (NROWS * D_)  // 262144 floats = 1 MB per split slice

typedef __attribute__((ext_vector_type(8))) short s8v;     // 8 bf16 (4 VGPRs)
typedef __attribute__((ext_vector_type(4))) float f4v;     // MFMA C/D

// ws layout (floats): [0..4]=acc sums, [1024..] partial slices
#define WS_PART_OFF 1024

__device__ inline unsigned int pack2bf(float f0, float f1) {
    unsigned int u0 = __float_as_uint(f0);
    unsigned int u1 = __float_as_uint(f1);
    u0 += 0x7fffu + ((u0 >> 16) & 1u);
    u1 += 0x7fffu + ((u1 >> 16) & 1u);
    return (u0 >> 16) | (u1 & 0xffff0000u);
}

// LDS-only barrier: waits lgkmcnt(0), leaves vmcnt (global prefetch) in flight.
__device__ inline void sync_lds() {
    __builtin_amdgcn_s_waitcnt(0xC07F);
    __builtin_amdgcn_s_barrier();
}

__device__ inline float wave_reduce(float v) {
    #pragma unroll
    for (int o = 32; o > 0; o >>= 1) v += __shfl_down(v, o, 64);
    return v;
}

// ---------------- misc body (512-thread blocks, fused into gemm grid) --------
__device__ void misc_body512(int bid,
                             const float* __restrict__ output_mle,
                             const float* __restrict__ attn,
                             const float* __restrict__ cover,
                             const int* __restrict__ trg,
                             const int* __restrict__ dec_mask,
                             const int* __restrict__ dec_len,
                             float* __restrict__ acc) {
    const int tid = threadIdx.x;
    if (bid < 32) {
        float s = 0.f;
        const float4* a4 = (const float4*)attn;
        const float4* c4 = (const float4*)cover;
        #pragma unroll 1
        for (int i4 = bid * 512 + tid; i4 < 65536; i4 += 32 * 512) {
            float4 a = a4[i4];
            float4 c = c4[i4];
            int b = i4 >> 14;
            int t = (i4 << 2) & (T_ - 1);
            int4 m = *(const int4*)&dec_mask[(b << 7) + t];
            s += m.x ? 0.f : fminf(a.x, c.x);
            s += m.y ? 0.f : fminf(a.y, c.y);
            s += m.z ? 0.f : fminf(a.z, c.z);
            s += m.w ? 0.f : fminf(a.w, c.w);
        }
        s = wave_reduce(s);
        if ((tid & 63) == 0) atomicAdd(&acc[2], s);
    } else if (bid == 32) {
        float lp = 0.f, cnt = 0.f;
        if (tid < NROWS) {
            int tg = trg[tid];
            if (tg != 0) {
                lp = __logf(output_mle[(size_t)tid * V_ + tg]);
                cnt = 1.f;
            }
        }
        lp = wave_reduce(lp); cnt = wave_reduce(cnt);
        if ((tid & 63) == 0) { atomicAdd(&acc[0], lp); atomicAdd(&acc[1], cnt); }
        if (tid < B_) atomicAdd(&acc[3], (float)dec_len[tid]);
    }
    // bids 33..39: nothing
}

// ---------------- GEMM: part[s] = exp(X)*W over split s (bf16 MFMA) ----------
// 512 threads (8 waves, wave-tile 64x32): 16 waves/CU (was 8) to fill the
// barrier-lockstep bubbles; per-thread staging halved (8 exp vs 16).
// XCD-cluster swizzle: all 16 tiles of split s land on XCD s&7 (misc offset
// NMISC is a multiple of 8 so blockIdx%8 still tracks the swizzle).
__launch_bounds__(512, 4)
__global__ void gemm_kernel(const float* __restrict__ X,
                            const float* __restrict__ W,
                            const float* __restrict__ attn,
                            const float* __restrict__ cover,
                            const int* __restrict__ trg,
                            const int* __restrict__ dec_mask,
                            const int* __restrict__ dec_len,
                            float* __restrict__ acc,
                            float* __restrict__ part,
                            int use_atomic) {
    __shared__ __align__(16) short As[128 * LDA];
    __shared__ __align__(16) short Bs[128 * LDB];

    if (blockIdx.x < NMISC) {
        misc_body512(blockIdx.x, X, attn, cover, trg, dec_mask, dec_len, acc);
        return;
    }
    const int g    = blockIdx.x - NMISC;
    const int xcd  = g & 7;
    const int j    = g >> 3;             // 0..63
    const int s    = xcd + 8 * (j >> 4); // 0..31 (bijective with tile)
    const int tile = j & 15;
    const int i0   = (tile & 3) * 128;
    const int d0   = (tile >> 2) * 128;
    const int ks   = s * KC;
    const int ke   = min(ks + KC, V_);

    const int tid  = threadIdx.x;
    const int lane = tid & 63;
    const int wave = tid >> 6;           // 0..7
    const int wm   = (wave >> 2) * 64;   // 2 M-groups
    const int wn   = (wave & 3) * 32;    // 4 N-groups
    const int l15  = lane & 15;
    const int l4   = lane >> 4;

    const int ar   = tid >> 2;           // A row 0..127
    const int ak   = (tid & 3) * 8;      // A k-octet
    const int bn2  = (tid & 63) * 2;     // B col pair
    const int bk   = (tid >> 6) * 4;     // B k-quad

    f4v acc_[4][2];
    #pragma unroll
    for (int a = 0; a < 4; a++)
        #pragma unroll
        for (int b = 0; b < 2; b++) acc_[a][b] = (f4v)0.f;

    auto stageA = [&](const float4 (&ab)[2]) {
        const float* f = (const float*)&ab[0];
        unsigned int au[4];
        #pragma unroll
        for (int p = 0; p < 4; p++)
            au[p] = pack2bf(__expf(f[2 * p]), __expf(f[2 * p + 1]));
        *(uint4*)&As[ar * LDA + ak] = *(const uint4*)&au[0];
    };
    auto stageB = [&](const float2 (&bb)[4]) {
        unsigned int r0[2], r1[2];
        r0[0] = pack2bf(bb[0].x, bb[1].x); r0[1] = pack2bf(bb[2].x, bb[3].x);
        r1[0] = pack2bf(bb[0].y, bb[1].y); r1[1] = pack2bf(bb[2].y, bb[3].y);
        *(uint2*)&Bs[bn2 * LDB + bk]       = *(const uint2*)&r0[0];
        *(uint2*)&Bs[(bn2 + 1) * LDB + bk] = *(const uint2*)&r1[0];
    };
    auto domfma = [&]() {
        s8v af[4], bfr[2];
        #pragma unroll
        for (int mi = 0; mi < 4; mi++)
            af[mi] = *(const s8v*)&As[(wm + mi * 16 + l15) * LDA + l4 * 8];
        #pragma unroll
        for (int ni = 0; ni < 2; ni++)
            bfr[ni] = *(const s8v*)&Bs[(wn + ni * 16 + l15) * LDB + l4 * 8];
        #pragma unroll
        for (int mi = 0; mi < 4; mi++)
            #pragma unroll
            for (int ni = 0; ni < 2; ni++)
                acc_[mi][ni] = __builtin_amdgcn_mfma_f32_16x16x32_bf16(
                    af[mi], bfr[ni], acc_[mi][ni], 0, 0, 0);
    };
    auto issue = [&](float4 (&ab)[2], float2 (&bb)[4], const float* ap, const float* bp) {
        ab[0] = *(const float4*)(ap);
        ab[1] = *(const float4*)(ap + 4);
        #pragma unroll
        for (int j2 = 0; j2 < 4; j2++) bb[j2] = *(const float2*)(bp + (size_t)j2 * D_);
    };

    if (ks + KC <= V_) {
        // full split: clamp-free pipelined loop; barriers never drain vmcnt
        const float* ap = X + (size_t)(i0 + ar) * V_ + ks + ak;
        const float* bp = W + d0 + bn2 + (size_t)(ks + bk) * D_;
        float4 a0[2], a1[2];
        float2 b0[4], b1[4];
        issue(a0, b0, ap, bp);
        #pragma unroll 1
        for (int it = 0; it < NIT; it += 2) {
            ap += BK; bp += (size_t)BK * D_;
            if (it + 1 < NIT) issue(a1, b1, ap, bp);
            sync_lds();
            stageA(a0); stageB(b0);
            sync_lds();
            domfma();

            ap += BK; bp += (size_t)BK * D_;
            if (it + 2 < NIT) issue(a0, b0, ap, bp);
            sync_lds();
            stageA(a1); stageB(b1);
            sync_lds();
            domfma();
        }
    } else {
        // last split: masked single-buffered loop
        const float* Abase = X + (size_t)(i0 + ar) * V_;
        const float* Bbase = W + d0 + bn2;
        for (int k0 = ks; k0 < ke; k0 += BK) {
            float4 ab[2];
            float2 bb[4];
            #pragma unroll
            for (int q = 0; q < 2; q++) {
                int gk = min(k0 + ak + q * 4, V_ - 4);
                ab[q] = *(const float4*)(Abase + gk);
            }
            #pragma unroll
            for (int j2 = 0; j2 < 4; j2++) {
                int gk = min(k0 + bk + j2, V_ - 1);
                bb[j2] = *(const float2*)(Bbase + (size_t)gk * D_);
            }
            sync_lds();
            {
                unsigned int au[4];
                const float* f = (const float*)&ab[0];
                #pragma unroll
                for (int p = 0; p < 4; p++) {
                    int g0 = k0 + ak + 2 * p;
                    float e0 = (g0     < ke) ? __expf(f[2 * p])     : 0.f;
                    float e1 = (g0 + 1 < ke) ? __expf(f[2 * p + 1]) : 0.f;
                    au[p] = pack2bf(e0, e1);
                }
                *(uint4*)&As[ar * LDA + ak] = *(const uint4*)&au[0];
            }
            {
                float xv[4], yv[4];
                #pragma unroll
                for (int j2 = 0; j2 < 4; j2++) {
                    bool ok = (k0 + bk + j2) < ke;
                    xv[j2] = ok ? bb[j2].x : 0.f;
                    yv[j2] = ok ? bb[j2].y : 0.f;
                }
                unsigned int r0[2], r1[2];
                r0[0] = pack2bf(xv[0], xv[1]); r0[1] = pack2bf(xv[2], xv[3]);
                r1[0] = pack2bf(yv[0], yv[1]); r1[1] = pack2bf(yv[2], yv[3]);
                *(uint2*)&Bs[bn2 * LDB + bk]       = *(const uint2*)&r0[0];
                *(uint2*)&Bs[(bn2 + 1) * LDB + bk] = *(const uint2*)&r1[0];
            }
            sync_lds();
            domfma();
        }
    }

    // epilogue: C/D layout col=lane&15, row=(lane>>4)*4+r
    float* dst = part + (use_atomic ? 0 : (size_t)s * SLICE);
    #pragma unroll
    for (int mi = 0; mi < 4; mi++) {
        #pragma unroll
        for (int ni = 0; ni < 2; ni++) {
            int col = d0 + wn + ni * 16 + l15;
            #pragma unroll
            for (int r = 0; r < 4; r++) {
                int row = i0 + wm + mi * 16 + l4 * 4 + r;
                if (use_atomic) atomicAdd(&dst[row * D_ + col], acc_[mi][ni][r]);
                else            dst[row * D_ + col] = acc_[mi][ni][r];
            }
        }
    }
}

// ---------------- ot: reduce slices + mean_i cos(pred_i, W[trg_i]) ----------------
// one row per block; 4 waves split slices; compile-time NSL => fully unrolled
// slice loop issues all loads up-front (no serial round-trips).
template<int NSL>
__global__ void ot_kernel(const float* __restrict__ part,
                          const float* __restrict__ W,
                          const int* __restrict__ trg,
                          float* __restrict__ acc) {
    __shared__ float Ps[4][D_];
    int wave = threadIdx.x >> 6, lane = threadIdx.x & 63;
    int row  = blockIdx.x;
    const size_t off = (size_t)row * D_ + lane * 8;

    float4 p0 = {0, 0, 0, 0}, p1 = {0, 0, 0, 0};
    #pragma unroll
    for (int si = 0; si < (NSL + 3) / 4; si++) {
        int s = wave + 4 * si;
        if (s < NSL) {
            const float4* ps = (const float4*)(part + (size_t)s * SLICE + off);
            float4 q0 = ps[0], q1 = ps[1];
            p0.x += q0.x; p0.y += q0.y; p0.z += q0.z; p0.w += q0.w;
            p1.x += q1.x; p1.y += q1.y; p1.z += q1.z; p1.w += q1.w;
        }
    }
    *(float4*)&Ps[wave][lane * 8]     = p0;
    *(float4*)&Ps[wave][lane * 8 + 4] = p1;
    __syncthreads();
    if (wave == 0) {
        float4 s0 = {0, 0, 0, 0}, s1 = {0, 0, 0, 0};
        #pragma unroll
        for (int w = 0; w < 4; w++) {
            float4 q0 = *(const float4*)&Ps[w][lane * 8];
            float4 q1 = *(const float4*)&Ps[w][lane * 8 + 4];
            s0.x += q0.x; s0.y += q0.y; s0.z += q0.z; s0.w += q0.w;
            s1.x += q1.x; s1.y += q1.y; s1.z += q1.z; s1.w += q1.w;
        }
        const float4* t4 = (const float4*)(W + (size_t)trg[row] * D_ + lane * 8);
        float4 t0 = t4[0], t1 = t4[1];

        float dot = s0.x * t0.x + s0.y * t0.y + s0.z * t0.z + s0.w * t0.w
                  + s1.x * t1.x + s1.y * t1.y + s1.z * t1.z + s1.w * t1.w;
        float nn  = s0.x * s0.x + s0.y * s0.y + s0.z * s0.z + s0.w * s0.w
                  + s1.x * s1.x + s1.y * s1.y + s1.z * s1.z + s1.w * s1.w;
        float tt  = t0.x * t0.x + t0.y * t0.y + t0.z * t0.z + t0.w * t0.w
                  + t1.x * t1.x + t1.y * t1.y + t1.z * t1.z + t1.w * t1.w;

        dot = wave_reduce(dot); nn = wave_reduce(nn); tt = wave_reduce(tt);
        if (lane == 0)
            atomicAdd(&acc[4], (dot / sqrtf(nn * tt)) * (1.0f / (float)NROWS));
    }
}

// ---------------- finalize ----------------
__global__ void finalize_kernel(const float* __restrict__ acc, float* __restrict__ out) {
    if (threadIdx.x == 0)
        out[0] = -acc[0] / acc[1] + acc[2] / acc[3] + GAMMA2_ + acc[4];
}

extern "C" void kernel_launch(void* const* d_in, const int* in_sizes, int n_in,
                              void* d_out, int out_size, void* d_ws, size_t ws_size,
                              hipStream_t stream) {
    const float* output_mle = (const float*)d_in[0];
    const float* attn       = (const float*)d_in[1];
    const float* cover      = (const float*)d_in[2];
    const int*   trg        = (const int*)d_in[3];
    const int*   dec_mask   = (const int*)d_in[4];
    const int*   dec_len    = (const int*)d_in[5];
    const float* W          = (const float*)d_in[6];
    float* out  = (float*)d_out;
    float* acc  = (float*)d_ws;
    float* part = acc + WS_PART_OFF;

    const size_t need = (size_t)WS_PART_OFF * 4 + (size_t)SPLITK * SLICE * 4;
    const bool partial = (ws_size >= need);   // constant across calls: graph-safe

    if (partial) {
        hipMemsetAsync(d_ws, 0, WS_PART_OFF * sizeof(float), stream);
    } else {
        hipMemsetAsync(d_ws, 0, (WS_PART_OFF + SLICE) * sizeof(float), stream);
    }
    gemm_kernel<<<NMISC + 16 * SPLITK, 512, 0, stream>>>(
        output_mle, W, attn, cover, trg, dec_mask, dec_len, acc, part, partial ? 0 : 1);
    if (partial) ot_kernel<SPLITK><<<NROWS, 256, 0, stream>>>(part, W, trg, acc);
    else         ot_kernel<1><<<NROWS, 256, 0, stream>>>(part, W, trg, acc);
    finalize_kernel<<<1, 64, 0, stream>>>(acc, out);
}